// Round 12
// baseline (435.225 us; speedup 1.0000x reference)
//
#include <hip/hip_runtime.h>
#include <hip/hip_bf16.h>

// Problem constants
#define B_   4
#define C_   2048
#define HH_  14
#define HW_  196      // 14*14
#define P_   784      // B_*HW_
#define PPAD_ 832     // 13*64 (gemm M padding)
#define K_   80
#define WD_  300
#define D_   1024

typedef float f32x4_t __attribute__((ext_vector_type(4)));
typedef short s16x8  __attribute__((ext_vector_type(8)));
typedef float f32x4a __attribute__((ext_vector_type(4)));
typedef unsigned short u16;
typedef u16 u16x4 __attribute__((ext_vector_type(4)));
typedef u16 u16x8 __attribute__((ext_vector_type(8)));

// ws layout (in float units)
#define XT_OFF    0                          // P_*C_        = 1605632
#define XTB_OFF   (XT_OFF + P_*C_)           // PPAD_*C_ u16
#define W1B_OFF   (XTB_OFF + (PPAD_*C_)/2)   // D_*C_ u16
#define IPROJ_OFF (W1B_OFF + (D_*C_)/2)      // P_*D_
#define W2TS_OFF  (IPROJ_OFF + P_*D_)        // WD_*D_
#define WPS_OFF   (W2TS_OFF + WD_*D_)        // K_*D_
#define VD2_OFF   (WPS_OFF + K_*D_)          // D_
#define VD2P_OFF  (VD2_OFF + D_)             // 32*D_
#define COEF_OFF  (VD2P_OFF + 32*D_)         // P_*K_

static __device__ __forceinline__ u16 f2bf(float x) {
  __hip_bfloat16 h = __float2bfloat16(x);
  return *(u16*)&h;
}

// ======== merged prep: roles by blockIdx.x =================================
// [0,2048)        : W1 fp32 -> bf16
// [2048,3840)     : transpose img -> xt fp32 + xtb bf16
// [3840,4160)     : transpose+scale W2 -> w2ts
// [4160,4288)     : vd2 partials: part[e/32][d] = sum_{32 e} W4[e]*W3[e,d]
// [4288,4296)     : zero xtb pad rows 784..831
#define PREP_BLOCKS 4296
__launch_bounds__(256)
__global__ void k_prep(const float* __restrict__ img, const float* __restrict__ W1,
                       const float* __restrict__ W2, const float* __restrict__ W3,
                       const float* __restrict__ W4,
                       float* __restrict__ xt, u16* __restrict__ xtb,
                       u16* __restrict__ w1b, float* __restrict__ w2ts,
                       float* __restrict__ vd2p) {
  __shared__ float tile[32][33];
  const int bid = blockIdx.x;
  const int t = threadIdx.x;
  if (bid < 2048) {                       // ---- W1 -> bf16
    int i = bid*256 + t;
    f32x4_t v = *(const f32x4_t*)&W1[(size_t)i*4];
    u16x4 o = { f2bf(v.x), f2bf(v.y), f2bf(v.z), f2bf(v.w) };
    *(u16x4*)&w1b[(size_t)i*4] = o;
  } else if (bid < 3840) {                // ---- transpose x
    int r = bid - 2048;
    int c0 = (r & 63) * 32;
    int hw0 = ((r >> 6) % 7) * 32;
    int b = r / 448;
    int tx = t & 31, ty = t >> 5;
    #pragma unroll
    for (int i = 0; i < 4; i++) {
      int c = c0 + ty + i*8, hw = hw0 + tx;
      float v = 0.f;
      if (hw < HW_) v = img[((size_t)b*C_ + c)*HW_ + hw];
      tile[ty + i*8][tx] = v;
    }
    __syncthreads();
    #pragma unroll
    for (int i = 0; i < 4; i++) {
      int hw = hw0 + ty + i*8, c = c0 + tx;
      if (hw < HW_) {
        float v = tile[tx][ty + i*8];
        size_t idx = ((size_t)(b*HW_ + hw))*C_ + c;
        xt[idx] = v;
        xtb[idx] = f2bf(v);
      }
    }
  } else if (bid < 4160) {                // ---- transpose+scale W2
    int r = bid - 3840;
    int d0 = (r & 31) * 32;
    int v0 = (r >> 5) * 32;
    int tx = t & 31, ty = t >> 5;
    #pragma unroll
    for (int i = 0; i < 4; i++) {
      int d = d0 + ty + i*8, v = v0 + tx;
      float val = 0.f;
      if (v < WD_) val = W2[(size_t)d*WD_ + v];
      tile[ty + i*8][tx] = val;
    }
    __syncthreads();
    const float s = 2.8853900817779268f;  // 2*log2(e)
    #pragma unroll
    for (int i = 0; i < 4; i++) {
      int v = v0 + ty + i*8, d = d0 + tx;
      if (v < WD_) w2ts[(size_t)v*D_ + d] = tile[tx][ty + i*8] * s;
    }
  } else if (bid < 4288) {                // ---- vd2 partials
    int r = bid - 4160;
    int d = (r & 3) * 256 + t;
    int e0 = (r >> 2) * 32;
    float acc = 0.f;
    #pragma unroll
    for (int q = 0; q < 32; q++)
      acc = fmaf(W4[e0 + q], W3[(size_t)(e0 + q)*D_ + d], acc);
    vd2p[(size_t)(r >> 2)*D_ + d] = acc;
  } else {                                // ---- zero xtb pad
    int r = bid - 4288;                   // 0..7
    u16x8 z = {0,0,0,0,0,0,0,0};
    #pragma unroll
    for (int i = 0; i < 6; i++) {
      size_t o = (size_t)P_*C_ + ((size_t)(r*256 + t)*6 + i)*8;
      *(u16x8*)&xtb[o] = z;
    }
  }
}

// ======== mid: gemm(208) + wproj(80) + vd2 finalize(1), role-split ========
#define GK_ 256
#define MID_BLOCKS 289
__launch_bounds__(256, 2)
__global__ void k_mid(const u16* __restrict__ xtb, const u16* __restrict__ w1b,
                      const float* __restrict__ wf, const float* __restrict__ w2ts,
                      const float* __restrict__ vd2p,
                      float* __restrict__ iproj, float* __restrict__ wps,
                      float* __restrict__ vd2) {
  __shared__ __align__(16) char smem[2*64*GK_*2];   // 64KB (gemm As+Bs)
  const int bid = blockIdx.x;
  const int t = threadIdx.x;
  if (bid < 208) {
    // ---- iproj = xtb(P,C) @ w1b^T(C,D), bf16 MFMA, BK=256, 64x64 tile ----
    u16* As = (u16*)smem;
    u16* Bs = As + 64*GK_;
    const int m0 = (bid >> 4) * 64, n0 = (bid & 15) * 64;
    const int wid = t >> 6, lane = t & 63;
    const int wm = wid >> 1, wn = wid & 1;
    const int lm = lane & 15, jr = lane >> 4;
    // staging: chunk c=i*256+t -> lds byte c*16; source chunk j = slot^(row&7)
    int offA[8], offB[8];
    u16* ldsA[8]; u16* ldsB[8];
    #pragma unroll
    for (int i = 0; i < 8; i++) {
      int c = i*256 + t;
      int row = c >> 5, js = c & 31;
      int j = js ^ (row & 7);
      offA[i] = (m0 + row) * C_ + j*8;
      offB[i] = (n0 + row) * C_ + j*8;
      ldsA[i] = &As[c*8];
      ldsB[i] = &Bs[c*8];
    }
    f32x4a acc[2][2] = {};
    for (int k0 = 0; k0 < C_; k0 += GK_) {
      #pragma unroll
      for (int i = 0; i < 8; i++)
        __builtin_amdgcn_global_load_lds((const __attribute__((address_space(1))) void*)(xtb + offA[i] + k0),
                                         (__attribute__((address_space(3))) void*)ldsA[i], 16, 0, 0);
      #pragma unroll
      for (int i = 0; i < 8; i++)
        __builtin_amdgcn_global_load_lds((const __attribute__((address_space(1))) void*)(w1b + offB[i] + k0),
                                         (__attribute__((address_space(3))) void*)ldsB[i], 16, 0, 0);
      __syncthreads();
      #pragma unroll
      for (int kk = 0; kk < 8; kk++) {
        int jx = ((kk*4 + jr) ^ (lm & 7)) * 8;
        s16x8 a0 = *(const s16x8*)&As[(wm*32 + lm)*GK_ + jx];
        s16x8 a1 = *(const s16x8*)&As[(wm*32 + 16 + lm)*GK_ + jx];
        s16x8 b0 = *(const s16x8*)&Bs[(wn*32 + lm)*GK_ + jx];
        s16x8 b1 = *(const s16x8*)&Bs[(wn*32 + 16 + lm)*GK_ + jx];
        acc[0][0] = __builtin_amdgcn_mfma_f32_16x16x32_bf16(a0, b0, acc[0][0], 0, 0, 0);
        acc[0][1] = __builtin_amdgcn_mfma_f32_16x16x32_bf16(a0, b1, acc[0][1], 0, 0, 0);
        acc[1][0] = __builtin_amdgcn_mfma_f32_16x16x32_bf16(a1, b0, acc[1][0], 0, 0, 0);
        acc[1][1] = __builtin_amdgcn_mfma_f32_16x16x32_bf16(a1, b1, acc[1][1], 0, 0, 0);
      }
      __syncthreads();
    }
    #pragma unroll
    for (int mi = 0; mi < 2; mi++)
      #pragma unroll
      for (int ni = 0; ni < 2; ni++)
        #pragma unroll
        for (int q = 0; q < 4; q++) {
          int prow = m0 + wm*32 + mi*16 + (lane>>4)*4 + q;
          int ncol = n0 + wn*32 + ni*16 + lm;
          if (prow < P_) iproj[(size_t)prow*D_ + ncol] = acc[mi][ni][q];
        }
  } else if (bid < 288) {
    // ---- wps[k,d] = sum_v wf[k,v]*w2ts[v,d] (scale folded into w2ts) ----
    float* wrow = (float*)smem;
    const int k = bid - 208;
    for (int i = t; i < WD_; i += 256) wrow[i] = wf[k*WD_ + i];
    __syncthreads();
    float4 acc = {0.f,0.f,0.f,0.f};
    const float4* w4 = (const float4*)w2ts;
    for (int v = 0; v < WD_; v++) {
      float s = wrow[v];
      float4 w = w4[(size_t)v*(D_/4) + t];
      acc.x = fmaf(s, w.x, acc.x); acc.y = fmaf(s, w.y, acc.y);
      acc.z = fmaf(s, w.z, acc.z); acc.w = fmaf(s, w.w, acc.w);
    }
    ((float4*)wps)[k*(D_/4) + t] = acc;
  } else {
    // ---- vd2[d] = -2 * sum_q vd2p[q][d] ----
    #pragma unroll
    for (int j = 0; j < 4; j++) {
      int d = j*256 + t;
      float s = 0.f;
      #pragma unroll
      for (int q = 0; q < 32; q++) s += vd2p[(size_t)q*D_ + d];
      vd2[d] = -2.0f * s;
    }
  }
}

// ======== coef[p,k] = sum_d vd2[d] * rcp(exp2(ip*wps)+1)   (S0 dropped:
// uniform shift cancels in softmax) ========================================
__launch_bounds__(320)
__global__ void k_coef(const float* __restrict__ iproj, const float* __restrict__ wps,
                       const float* __restrict__ vd2, float* __restrict__ coef) {
  __shared__ float ipd[D_];
  __shared__ float v2s[D_];
  const int p = blockIdx.x;
  const int t = threadIdx.x;
  for (int i = t; i < D_; i += 320) {
    ipd[i] = iproj[(size_t)p*D_ + i];
    v2s[i] = vd2[i];
  }
  __syncthreads();
  const int k = t >> 2, dq = t & 3;      // 4 lanes per k, each a 256-d quarter
  const float4* wv  = (const float4*)&wps[(size_t)k*D_ + dq*256];
  const float4* ip4 = (const float4*)&ipd[dq*256];
  const float4* v24 = (const float4*)&v2s[dq*256];
  float acc = 0.f;
  for (int q = 0; q < 64; q++) {
    float4 w  = wv[q];
    float4 ip = ip4[q];
    float4 v2 = v24[q];
    float r0 = __builtin_amdgcn_rcpf(__builtin_amdgcn_exp2f(ip.x*w.x) + 1.0f);
    float r1 = __builtin_amdgcn_rcpf(__builtin_amdgcn_exp2f(ip.y*w.y) + 1.0f);
    float r2 = __builtin_amdgcn_rcpf(__builtin_amdgcn_exp2f(ip.z*w.z) + 1.0f);
    float r3 = __builtin_amdgcn_rcpf(__builtin_amdgcn_exp2f(ip.w*w.w) + 1.0f);
    acc = fmaf(v2.x, r0, acc);
    acc = fmaf(v2.y, r1, acc);
    acc = fmaf(v2.z, r2, acc);
    acc = fmaf(v2.w, r3, acc);
  }
  acc += __shfl_xor(acc, 1);
  acc += __shfl_xor(acc, 2);
  if (dq == 0) coef[(size_t)p*K_ + k] = acc;
}

// ======== softmax over HW per (b,k) + fused semantic reduction =============
// 64 threads = 1 wave per (b,k). After sm is known, each thread accumulates
// 8 x 4 c-columns (c = t*4 + j*256) of semantic[b,k,:] over 196 positions.
__launch_bounds__(64)
__global__ void k_softmax_sem(const float* __restrict__ coef, const float* __restrict__ xt,
                              float* __restrict__ sm, float* __restrict__ semantic) {
  __shared__ float srow[HW_];
  int bk = blockIdx.x; int b = bk / K_, k = bk % K_;
  int t = threadIdx.x;                  // 64 threads = 1 wave
  float v[4]; float mx = -1e30f;
  #pragma unroll
  for (int i = 0; i < 4; i++) {
    int hw = t + i*64;
    v[i] = (hw < HW_) ? coef[(size_t)(b*HW_ + hw)*K_ + k] : -1e30f;
    mx = fmaxf(mx, v[i]);
  }
  #pragma unroll
  for (int off = 32; off > 0; off >>= 1) mx = fmaxf(mx, __shfl_xor(mx, off));
  float e[4]; float sum = 0.f;
  #pragma unroll
  for (int i = 0; i < 4; i++) {
    int hw = t + i*64;
    e[i] = (hw < HW_) ? __builtin_amdgcn_exp2f((v[i]-mx)*1.4426950408889634f) : 0.f;
    sum += e[i];
  }
  #pragma unroll
  for (int off = 32; off > 0; off >>= 1) sum += __shfl_xor(sum, off);
  float rs = 1.0f / sum;
  #pragma unroll
  for (int i = 0; i < 4; i++) {
    int hw = t + i*64;
    if (hw < HW_) {
      float s = e[i]*rs;
      sm[(size_t)(b*HW_ + hw)*K_ + k] = s;
      srow[hw] = s;
    }
  }
  __syncthreads();
  // semantic[b,k,c]: thread t owns c = t*4 + 256*j (floats), j=0..7
  f32x4_t acc[8];
  #pragma unroll
  for (int j = 0; j < 8; j++) acc[j] = (f32x4_t){0.f,0.f,0.f,0.f};
  const float* xb = xt + (size_t)b*HW_*C_;
  for (int hw = 0; hw < HW_; hw++) {
    float s = srow[hw];
    const float* xr = xb + (size_t)hw*C_ + t*4;
    #pragma unroll
    for (int j = 0; j < 8; j++) {
      f32x4_t xv = *(const f32x4_t*)(xr + j*256);
      acc[j].x = fmaf(xv.x, s, acc[j].x);
      acc[j].y = fmaf(xv.y, s, acc[j].y);
      acc[j].z = fmaf(xv.z, s, acc[j].z);
      acc[j].w = fmaf(xv.w, s, acc[j].w);
    }
  }
  float* so = semantic + ((size_t)(b*K_ + k))*C_ + t*4;
  #pragma unroll
  for (int j = 0; j < 8; j++)
    *(f32x4_t*)(so + j*256) = acc[j];
}

// ======== fwc: PURE grid-stride global-address-order nt sweep (r9) =========
#define FWC_BLOCKS 2048
__launch_bounds__(256)
__global__ void k_fwc(const float* __restrict__ xt, const float* __restrict__ sm,
                      float* __restrict__ fwc) {
  const int t = threadIdx.x;
  const size_t N4 = (size_t)P_*K_*(C_/4);            // 32,112,640 float4
  const size_t stride4 = (size_t)FWC_BLOCKS*256;
  size_t i4 = (size_t)blockIdx.x*256 + t;
  for (; i4 < N4; i4 += stride4) {
    int c4 = (int)(i4 & (C_/4 - 1));                 // 0..511
    int pk = (int)(i4 >> 9);                         // p*K_ + k
    int p  = pk / K_;                                // magic-mul div
    float s = sm[pk];                                // sm is pk-linear
    f32x4_t xv = *(const f32x4_t*)&xt[(size_t)p*C_ + c4*4];
    __builtin_nontemporal_store(xv * s, (f32x4_t*)&fwc[i4*4]);
  }
}

extern "C" void kernel_launch(void* const* d_in, const int* in_sizes, int n_in,
                              void* d_out, int out_size, void* d_ws, size_t ws_size,
                              hipStream_t stream) {
  const float* img  = (const float*)d_in[0];
  const float* wf   = (const float*)d_in[1];
  const float* W1   = (const float*)d_in[2];
  const float* W2   = (const float*)d_in[3];
  const float* W3   = (const float*)d_in[4];
  const float* W4   = (const float*)d_in[6];

  float* out = (float*)d_out;
  float* semantic = out;                                    // B*K*C
  float* fwc      = out + (size_t)B_*K_*C_;                 // B*HW*K*C
  float* sm       = fwc + (size_t)P_*K_*C_;                 // B*HW*K

  float* ws    = (float*)d_ws;
  float* xt    = ws + XT_OFF;
  u16*   xtb   = (u16*)(ws + XTB_OFF);
  u16*   w1b   = (u16*)(ws + W1B_OFF);
  float* iproj = ws + IPROJ_OFF;
  float* w2ts  = ws + W2TS_OFF;
  float* wps   = ws + WPS_OFF;
  float* vd2   = ws + VD2_OFF;
  float* vd2p  = ws + VD2P_OFF;
  float* coef  = ws + COEF_OFF;

  k_prep<<<PREP_BLOCKS, 256, 0, stream>>>(img, W1, W2, W3, W4, xt, xtb, w1b, w2ts, vd2p);
  k_mid<<<MID_BLOCKS, 256, 0, stream>>>(xtb, w1b, wf, w2ts, vd2p, iproj, wps, vd2);
  k_coef<<<P_, 320, 0, stream>>>(iproj, wps, vd2, coef);
  k_softmax_sem<<<B_*K_, 64, 0, stream>>>(coef, xt, sm, semantic);
  k_fwc<<<FWC_BLOCKS, 256, 0, stream>>>(xt, sm, fwc);
}

// Round 13
// 306.788 us; speedup vs baseline: 1.4186x; 1.4186x over previous
//
#include <hip/hip_runtime.h>
#include <hip/hip_bf16.h>

// Problem constants
#define B_   4
#define C_   2048
#define HH_  14
#define HW_  196      // 14*14
#define P_   784      // B_*HW_
#define PPAD_ 832     // 13*64 (gemm M padding)
#define K_   80
#define WD_  300
#define D_   1024

typedef float f32x4_t __attribute__((ext_vector_type(4)));
typedef short s16x8  __attribute__((ext_vector_type(8)));
typedef float f32x4a __attribute__((ext_vector_type(4)));
typedef unsigned short u16;
typedef u16 u16x4 __attribute__((ext_vector_type(4)));
typedef u16 u16x8 __attribute__((ext_vector_type(8)));

// ws layout (in float units)
#define XT_OFF    0                          // P_*C_        = 1605632
#define XTB_OFF   (XT_OFF + P_*C_)           // PPAD_*C_ u16
#define W1B_OFF   (XTB_OFF + (PPAD_*C_)/2)   // D_*C_ u16
#define IPROJ_OFF (W1B_OFF + (D_*C_)/2)      // P_*D_
#define W2TS_OFF  (IPROJ_OFF + P_*D_)        // WD_*D_
#define WPS_OFF   (W2TS_OFF + WD_*D_)        // K_*D_
#define VD2_OFF   (WPS_OFF + K_*D_)          // D_
#define VD2P_OFF  (VD2_OFF + D_)             // 32*D_
#define COEF_OFF  (VD2P_OFF + 32*D_)         // P_*K_

static __device__ __forceinline__ u16 f2bf(float x) {
  __hip_bfloat16 h = __float2bfloat16(x);
  return *(u16*)&h;
}

// ======== merged prep: roles by blockIdx.x =================================
// [0,2048)        : W1 fp32 -> bf16
// [2048,3840)     : transpose img -> xt fp32 + xtb bf16
// [3840,4160)     : transpose+scale W2 -> w2ts
// [4160,4288)     : vd2 partials: part[e/32][d] = sum_{32 e} W4[e]*W3[e,d]
// [4288,4296)     : zero xtb pad rows 784..831
#define PREP_BLOCKS 4296
__launch_bounds__(256)
__global__ void k_prep(const float* __restrict__ img, const float* __restrict__ W1,
                       const float* __restrict__ W2, const float* __restrict__ W3,
                       const float* __restrict__ W4,
                       float* __restrict__ xt, u16* __restrict__ xtb,
                       u16* __restrict__ w1b, float* __restrict__ w2ts,
                       float* __restrict__ vd2p) {
  __shared__ float tile[32][33];
  const int bid = blockIdx.x;
  const int t = threadIdx.x;
  if (bid < 2048) {                       // ---- W1 -> bf16
    int i = bid*256 + t;
    f32x4_t v = *(const f32x4_t*)&W1[(size_t)i*4];
    u16x4 o = { f2bf(v.x), f2bf(v.y), f2bf(v.z), f2bf(v.w) };
    *(u16x4*)&w1b[(size_t)i*4] = o;
  } else if (bid < 3840) {                // ---- transpose x
    int r = bid - 2048;
    int c0 = (r & 63) * 32;
    int hw0 = ((r >> 6) % 7) * 32;
    int b = r / 448;
    int tx = t & 31, ty = t >> 5;
    #pragma unroll
    for (int i = 0; i < 4; i++) {
      int c = c0 + ty + i*8, hw = hw0 + tx;
      float v = 0.f;
      if (hw < HW_) v = img[((size_t)b*C_ + c)*HW_ + hw];
      tile[ty + i*8][tx] = v;
    }
    __syncthreads();
    #pragma unroll
    for (int i = 0; i < 4; i++) {
      int hw = hw0 + ty + i*8, c = c0 + tx;
      if (hw < HW_) {
        float v = tile[tx][ty + i*8];
        size_t idx = ((size_t)(b*HW_ + hw))*C_ + c;
        xt[idx] = v;
        xtb[idx] = f2bf(v);
      }
    }
  } else if (bid < 4160) {                // ---- transpose+scale W2
    int r = bid - 3840;
    int d0 = (r & 31) * 32;
    int v0 = (r >> 5) * 32;
    int tx = t & 31, ty = t >> 5;
    #pragma unroll
    for (int i = 0; i < 4; i++) {
      int d = d0 + ty + i*8, v = v0 + tx;
      float val = 0.f;
      if (v < WD_) val = W2[(size_t)d*WD_ + v];
      tile[ty + i*8][tx] = val;
    }
    __syncthreads();
    const float s = 2.8853900817779268f;  // 2*log2(e)
    #pragma unroll
    for (int i = 0; i < 4; i++) {
      int v = v0 + ty + i*8, d = d0 + tx;
      if (v < WD_) w2ts[(size_t)v*D_ + d] = tile[tx][ty + i*8] * s;
    }
  } else if (bid < 4288) {                // ---- vd2 partials
    int r = bid - 4160;
    int d = (r & 3) * 256 + t;
    int e0 = (r >> 2) * 32;
    float acc = 0.f;
    #pragma unroll
    for (int q = 0; q < 32; q++)
      acc = fmaf(W4[e0 + q], W3[(size_t)(e0 + q)*D_ + d], acc);
    vd2p[(size_t)(r >> 2)*D_ + d] = acc;
  } else {                                // ---- zero xtb pad
    int r = bid - 4288;                   // 0..7
    u16x8 z = {0,0,0,0,0,0,0,0};
    #pragma unroll
    for (int i = 0; i < 6; i++) {
      size_t o = (size_t)P_*C_ + ((size_t)(r*256 + t)*6 + i)*8;
      *(u16x8*)&xtb[o] = z;
    }
  }
}

// ======== mid: gemm(208) + wproj(80) + vd2 finalize(1), role-split ========
#define GK_ 256
#define MID_BLOCKS 289
__launch_bounds__(256, 2)
__global__ void k_mid(const u16* __restrict__ xtb, const u16* __restrict__ w1b,
                      const float* __restrict__ wf, const float* __restrict__ w2ts,
                      const float* __restrict__ vd2p,
                      float* __restrict__ iproj, float* __restrict__ wps,
                      float* __restrict__ vd2) {
  __shared__ __align__(16) char smem[2*64*GK_*2];   // 64KB (gemm As+Bs)
  const int bid = blockIdx.x;
  const int t = threadIdx.x;
  if (bid < 208) {
    // ---- iproj = xtb(P,C) @ w1b^T(C,D), bf16 MFMA, BK=256, 64x64 tile ----
    u16* As = (u16*)smem;
    u16* Bs = As + 64*GK_;
    const int m0 = (bid >> 4) * 64, n0 = (bid & 15) * 64;
    const int wid = t >> 6, lane = t & 63;
    const int wm = wid >> 1, wn = wid & 1;
    const int lm = lane & 15, jr = lane >> 4;
    // staging: chunk c=i*256+t -> lds byte c*16; source chunk j = slot^(row&7)
    int offA[8], offB[8];
    u16* ldsA[8]; u16* ldsB[8];
    #pragma unroll
    for (int i = 0; i < 8; i++) {
      int c = i*256 + t;
      int row = c >> 5, js = c & 31;
      int j = js ^ (row & 7);
      offA[i] = (m0 + row) * C_ + j*8;
      offB[i] = (n0 + row) * C_ + j*8;
      ldsA[i] = &As[c*8];
      ldsB[i] = &Bs[c*8];
    }
    f32x4a acc[2][2] = {};
    for (int k0 = 0; k0 < C_; k0 += GK_) {
      #pragma unroll
      for (int i = 0; i < 8; i++)
        __builtin_amdgcn_global_load_lds((const __attribute__((address_space(1))) void*)(xtb + offA[i] + k0),
                                         (__attribute__((address_space(3))) void*)ldsA[i], 16, 0, 0);
      #pragma unroll
      for (int i = 0; i < 8; i++)
        __builtin_amdgcn_global_load_lds((const __attribute__((address_space(1))) void*)(w1b + offB[i] + k0),
                                         (__attribute__((address_space(3))) void*)ldsB[i], 16, 0, 0);
      __syncthreads();
      #pragma unroll
      for (int kk = 0; kk < 8; kk++) {
        int jx = ((kk*4 + jr) ^ (lm & 7)) * 8;
        s16x8 a0 = *(const s16x8*)&As[(wm*32 + lm)*GK_ + jx];
        s16x8 a1 = *(const s16x8*)&As[(wm*32 + 16 + lm)*GK_ + jx];
        s16x8 b0 = *(const s16x8*)&Bs[(wn*32 + lm)*GK_ + jx];
        s16x8 b1 = *(const s16x8*)&Bs[(wn*32 + 16 + lm)*GK_ + jx];
        acc[0][0] = __builtin_amdgcn_mfma_f32_16x16x32_bf16(a0, b0, acc[0][0], 0, 0, 0);
        acc[0][1] = __builtin_amdgcn_mfma_f32_16x16x32_bf16(a0, b1, acc[0][1], 0, 0, 0);
        acc[1][0] = __builtin_amdgcn_mfma_f32_16x16x32_bf16(a1, b0, acc[1][0], 0, 0, 0);
        acc[1][1] = __builtin_amdgcn_mfma_f32_16x16x32_bf16(a1, b1, acc[1][1], 0, 0, 0);
      }
      __syncthreads();
    }
    #pragma unroll
    for (int mi = 0; mi < 2; mi++)
      #pragma unroll
      for (int ni = 0; ni < 2; ni++)
        #pragma unroll
        for (int q = 0; q < 4; q++) {
          int prow = m0 + wm*32 + mi*16 + (lane>>4)*4 + q;
          int ncol = n0 + wn*32 + ni*16 + lm;
          if (prow < P_) iproj[(size_t)prow*D_ + ncol] = acc[mi][ni][q];
        }
  } else if (bid < 288) {
    // ---- wps[k,d] = sum_v wf[k,v]*w2ts[v,d] (scale folded into w2ts) ----
    float* wrow = (float*)smem;
    const int k = bid - 208;
    for (int i = t; i < WD_; i += 256) wrow[i] = wf[k*WD_ + i];
    __syncthreads();
    float4 acc = {0.f,0.f,0.f,0.f};
    const float4* w4 = (const float4*)w2ts;
    for (int v = 0; v < WD_; v++) {
      float s = wrow[v];
      float4 w = w4[(size_t)v*(D_/4) + t];
      acc.x = fmaf(s, w.x, acc.x); acc.y = fmaf(s, w.y, acc.y);
      acc.z = fmaf(s, w.z, acc.z); acc.w = fmaf(s, w.w, acc.w);
    }
    ((float4*)wps)[k*(D_/4) + t] = acc;
  } else {
    // ---- vd2[d] = -2 * sum_q vd2p[q][d] ----
    #pragma unroll
    for (int j = 0; j < 4; j++) {
      int d = j*256 + t;
      float s = 0.f;
      #pragma unroll
      for (int q = 0; q < 32; q++) s += vd2p[(size_t)q*D_ + d];
      vd2[d] = -2.0f * s;
    }
  }
}

// ======== coef[p,k] = sum_d vd2[d] * rcp(exp2(ip*wps)+1)   (S0 dropped:
// uniform shift cancels in softmax) ========================================
__launch_bounds__(320)
__global__ void k_coef(const float* __restrict__ iproj, const float* __restrict__ wps,
                       const float* __restrict__ vd2, float* __restrict__ coef) {
  __shared__ float ipd[D_];
  __shared__ float v2s[D_];
  const int p = blockIdx.x;
  const int t = threadIdx.x;
  for (int i = t; i < D_; i += 320) {
    ipd[i] = iproj[(size_t)p*D_ + i];
    v2s[i] = vd2[i];
  }
  __syncthreads();
  const int k = t >> 2, dq = t & 3;      // 4 lanes per k, each a 256-d quarter
  const float4* wv  = (const float4*)&wps[(size_t)k*D_ + dq*256];
  const float4* ip4 = (const float4*)&ipd[dq*256];
  const float4* v24 = (const float4*)&v2s[dq*256];
  float acc = 0.f;
  for (int q = 0; q < 64; q++) {
    float4 w  = wv[q];
    float4 ip = ip4[q];
    float4 v2 = v24[q];
    float r0 = __builtin_amdgcn_rcpf(__builtin_amdgcn_exp2f(ip.x*w.x) + 1.0f);
    float r1 = __builtin_amdgcn_rcpf(__builtin_amdgcn_exp2f(ip.y*w.y) + 1.0f);
    float r2 = __builtin_amdgcn_rcpf(__builtin_amdgcn_exp2f(ip.z*w.z) + 1.0f);
    float r3 = __builtin_amdgcn_rcpf(__builtin_amdgcn_exp2f(ip.w*w.w) + 1.0f);
    acc = fmaf(v2.x, r0, acc);
    acc = fmaf(v2.y, r1, acc);
    acc = fmaf(v2.z, r2, acc);
    acc = fmaf(v2.w, r3, acc);
  }
  acc += __shfl_xor(acc, 1);
  acc += __shfl_xor(acc, 2);
  if (dq == 0) coef[(size_t)p*K_ + k] = acc;
}

// ======== softmax over HW per (b,k) ========================================
__global__ void k_softmax(const float* __restrict__ coef, float* __restrict__ sm) {
  int bk = blockIdx.x; int b = bk / K_, k = bk % K_;
  int t = threadIdx.x;                  // 64 threads = 1 wave
  float v[4]; float mx = -1e30f;
  #pragma unroll
  for (int i = 0; i < 4; i++) {
    int hw = t + i*64;
    v[i] = (hw < HW_) ? coef[(size_t)(b*HW_ + hw)*K_ + k] : -1e30f;
    mx = fmaxf(mx, v[i]);
  }
  #pragma unroll
  for (int off = 32; off > 0; off >>= 1) mx = fmaxf(mx, __shfl_xor(mx, off));
  float e[4]; float sum = 0.f;
  #pragma unroll
  for (int i = 0; i < 4; i++) {
    int hw = t + i*64;
    e[i] = (hw < HW_) ? __builtin_amdgcn_exp2f((v[i]-mx)*1.4426950408889634f) : 0.f;
    sum += e[i];
  }
  #pragma unroll
  for (int off = 32; off > 0; off >>= 1) sum += __shfl_xor(sum, off);
  float rs = 1.0f / sum;
  #pragma unroll
  for (int i = 0; i < 4; i++) {
    int hw = t + i*64;
    if (hw < HW_) sm[(size_t)(b*HW_ + hw)*K_ + k] = e[i]*rs;
  }
}

// ======== fwc write + semantic (r9 structure) ==============================
// sem: 32 blocks, xt read once per (b,c-chunk), 80 k-accumulators.
// fwc: grid-stride global-address-order nt sweep; NEW: 2 adjacent float4
// (32B) per thread per iteration -> 2x stores in flight, ~31 iterations.
#define SEM_BLOCKS 32
#define FWC_BLOCKS 2048
__launch_bounds__(256)
__global__ void k_fwc_sem(const float* __restrict__ xt, const float* __restrict__ sm,
                          float* __restrict__ fwc, float* __restrict__ semantic) {
  const int bid = blockIdx.x;
  const int t = threadIdx.x;
  if (bid < SEM_BLOCKS) {
    // ---- semantic[b,k,c] = sum_hw xt[(b,hw),c]*sm[(b,hw),k] ----
    const int b = bid >> 3;
    const int c = (bid & 7) * 256 + t;
    float acc[K_];
    #pragma unroll
    for (int k = 0; k < K_; k++) acc[k] = 0.f;
    const float* smb = sm + (size_t)b*HW_*K_;
    const float* xb  = xt + (size_t)b*HW_*C_ + c;
    for (int hw = 0; hw < HW_; hw++) {
      float xv = xb[(size_t)hw*C_];
      #pragma unroll
      for (int k4 = 0; k4 < K_/4; k4++) {
        f32x4_t sv = *(const f32x4_t*)&smb[hw*K_ + k4*4];
        acc[k4*4+0] = fmaf(xv, sv.x, acc[k4*4+0]);
        acc[k4*4+1] = fmaf(xv, sv.y, acc[k4*4+1]);
        acc[k4*4+2] = fmaf(xv, sv.z, acc[k4*4+2]);
        acc[k4*4+3] = fmaf(xv, sv.w, acc[k4*4+3]);
      }
    }
    #pragma unroll
    for (int k = 0; k < K_; k++)
      semantic[((size_t)(b*K_ + k))*C_ + c] = acc[k];
  } else {
    // ---- fwc[p,k,c] = xt[p,c]*sm[p,k], linear nt sweep, 32B/thread ----
    const size_t N8 = (size_t)P_*K_*(C_/8);            // 16,056,320 pairs
    const size_t stride8 = (size_t)FWC_BLOCKS*256;
    size_t i8 = (size_t)(bid - SEM_BLOCKS)*256 + t;
    for (; i8 < N8; i8 += stride8) {
      size_t i4 = i8*2;
      int c4 = (int)(i4 & (C_/4 - 1));                 // 0..511 (even)
      int pk = (int)(i4 >> 9);                         // p*K_ + k
      int p  = pk / K_;                                // magic-mul div
      float s = sm[pk];                                // sm is pk-linear
      const float* xr = &xt[(size_t)p*C_ + c4*4];
      f32x4_t a = *(const f32x4_t*)xr;
      f32x4_t b = *(const f32x4_t*)(xr + 4);
      float* o = &fwc[i4*4];
      __builtin_nontemporal_store(a * s, (f32x4_t*)o);
      __builtin_nontemporal_store(b * s, (f32x4_t*)(o + 4));
    }
  }
}

extern "C" void kernel_launch(void* const* d_in, const int* in_sizes, int n_in,
                              void* d_out, int out_size, void* d_ws, size_t ws_size,
                              hipStream_t stream) {
  const float* img  = (const float*)d_in[0];
  const float* wf   = (const float*)d_in[1];
  const float* W1   = (const float*)d_in[2];
  const float* W2   = (const float*)d_in[3];
  const float* W3   = (const float*)d_in[4];
  const float* W4   = (const float*)d_in[6];

  float* out = (float*)d_out;
  float* semantic = out;                                    // B*K*C
  float* fwc      = out + (size_t)B_*K_*C_;                 // B*HW*K*C
  float* sm       = fwc + (size_t)P_*K_*C_;                 // B*HW*K

  float* ws    = (float*)d_ws;
  float* xt    = ws + XT_OFF;
  u16*   xtb   = (u16*)(ws + XTB_OFF);
  u16*   w1b   = (u16*)(ws + W1B_OFF);
  float* iproj = ws + IPROJ_OFF;
  float* w2ts  = ws + W2TS_OFF;
  float* wps   = ws + WPS_OFF;
  float* vd2   = ws + VD2_OFF;
  float* vd2p  = ws + VD2P_OFF;
  float* coef  = ws + COEF_OFF;

  k_prep<<<PREP_BLOCKS, 256, 0, stream>>>(img, W1, W2, W3, W4, xt, xtb, w1b, w2ts, vd2p);
  k_mid<<<MID_BLOCKS, 256, 0, stream>>>(xtb, w1b, wf, w2ts, vd2p, iproj, wps, vd2);
  k_coef<<<P_, 320, 0, stream>>>(iproj, wps, vd2, coef);
  k_softmax<<<B_*K_, 64, 0, stream>>>(coef, sm);
  k_fwc_sem<<<SEM_BLOCKS + FWC_BLOCKS, 256, 0, stream>>>(xt, sm, fwc, semantic);
}

// Round 14
// 213.015 us; speedup vs baseline: 2.0432x; 1.4402x over previous
//
#include <hip/hip_runtime.h>
#include <hip/hip_bf16.h>

// Problem constants
#define B_   4
#define C_   2048
#define HH_  14
#define HW_  196      // 14*14
#define P_   784      // B_*HW_
#define PPAD_ 832     // 13*64 (gemm M padding)
#define K_   80
#define WD_  300
#define D_   1024

typedef float f32x4_t __attribute__((ext_vector_type(4)));
typedef short s16x8  __attribute__((ext_vector_type(8)));
typedef float f32x4a __attribute__((ext_vector_type(4)));
typedef unsigned short u16;
typedef u16 u16x4 __attribute__((ext_vector_type(4)));
typedef u16 u16x8 __attribute__((ext_vector_type(8)));

// ws layout (in float units)
#define XT_OFF    0                          // P_*C_        = 1605632
#define XTB_OFF   (XT_OFF + P_*C_)           // PPAD_*C_ u16
#define W1B_OFF   (XTB_OFF + (PPAD_*C_)/2)   // D_*C_ u16
#define IPROJ_OFF (W1B_OFF + (D_*C_)/2)      // P_*D_
#define W2TS_OFF  (IPROJ_OFF + P_*D_)        // WD_*D_
#define WPS_OFF   (W2TS_OFF + WD_*D_)        // K_*D_
#define VD2_OFF   (WPS_OFF + K_*D_)          // D_
#define VD2P_OFF  (VD2_OFF + D_)             // 32*D_
#define COEF_OFF  (VD2P_OFF + 32*D_)         // P_*K_

static __device__ __forceinline__ u16 f2bf(float x) {
  __hip_bfloat16 h = __float2bfloat16(x);
  return *(u16*)&h;
}

// ======== merged prep: roles by blockIdx.x =================================
// [0,2048)        : W1 fp32 -> bf16
// [2048,3840)     : transpose img -> xt fp32 + xtb bf16
// [3840,4160)     : transpose+scale W2 -> w2ts
// [4160,4288)     : vd2 partials: part[e/32][d] = sum_{32 e} W4[e]*W3[e,d]
// [4288,4296)     : zero xtb pad rows 784..831
#define PREP_BLOCKS 4296
__launch_bounds__(256)
__global__ void k_prep(const float* __restrict__ img, const float* __restrict__ W1,
                       const float* __restrict__ W2, const float* __restrict__ W3,
                       const float* __restrict__ W4,
                       float* __restrict__ xt, u16* __restrict__ xtb,
                       u16* __restrict__ w1b, float* __restrict__ w2ts,
                       float* __restrict__ vd2p) {
  __shared__ float tile[32][33];
  const int bid = blockIdx.x;
  const int t = threadIdx.x;
  if (bid < 2048) {                       // ---- W1 -> bf16
    int i = bid*256 + t;
    f32x4_t v = *(const f32x4_t*)&W1[(size_t)i*4];
    u16x4 o = { f2bf(v.x), f2bf(v.y), f2bf(v.z), f2bf(v.w) };
    *(u16x4*)&w1b[(size_t)i*4] = o;
  } else if (bid < 3840) {                // ---- transpose x
    int r = bid - 2048;
    int c0 = (r & 63) * 32;
    int hw0 = ((r >> 6) % 7) * 32;
    int b = r / 448;
    int tx = t & 31, ty = t >> 5;
    #pragma unroll
    for (int i = 0; i < 4; i++) {
      int c = c0 + ty + i*8, hw = hw0 + tx;
      float v = 0.f;
      if (hw < HW_) v = img[((size_t)b*C_ + c)*HW_ + hw];
      tile[ty + i*8][tx] = v;
    }
    __syncthreads();
    #pragma unroll
    for (int i = 0; i < 4; i++) {
      int hw = hw0 + ty + i*8, c = c0 + tx;
      if (hw < HW_) {
        float v = tile[tx][ty + i*8];
        size_t idx = ((size_t)(b*HW_ + hw))*C_ + c;
        xt[idx] = v;
        xtb[idx] = f2bf(v);
      }
    }
  } else if (bid < 4160) {                // ---- transpose+scale W2
    int r = bid - 3840;
    int d0 = (r & 31) * 32;
    int v0 = (r >> 5) * 32;
    int tx = t & 31, ty = t >> 5;
    #pragma unroll
    for (int i = 0; i < 4; i++) {
      int d = d0 + ty + i*8, v = v0 + tx;
      float val = 0.f;
      if (v < WD_) val = W2[(size_t)d*WD_ + v];
      tile[ty + i*8][tx] = val;
    }
    __syncthreads();
    const float s = 2.8853900817779268f;  // 2*log2(e)
    #pragma unroll
    for (int i = 0; i < 4; i++) {
      int v = v0 + ty + i*8, d = d0 + tx;
      if (v < WD_) w2ts[(size_t)v*D_ + d] = tile[tx][ty + i*8] * s;
    }
  } else if (bid < 4288) {                // ---- vd2 partials
    int r = bid - 4160;
    int d = (r & 3) * 256 + t;
    int e0 = (r >> 2) * 32;
    float acc = 0.f;
    #pragma unroll
    for (int q = 0; q < 32; q++)
      acc = fmaf(W4[e0 + q], W3[(size_t)(e0 + q)*D_ + d], acc);
    vd2p[(size_t)(r >> 2)*D_ + d] = acc;
  } else {                                // ---- zero xtb pad
    int r = bid - 4288;                   // 0..7
    u16x8 z = {0,0,0,0,0,0,0,0};
    #pragma unroll
    for (int i = 0; i < 6; i++) {
      size_t o = (size_t)P_*C_ + ((size_t)(r*256 + t)*6 + i)*8;
      *(u16x8*)&xtb[o] = z;
    }
  }
}

// ======== mid: gemm(208) + wproj(80) + vd2 finalize(1), role-split ========
#define GK_ 256
#define MID_BLOCKS 289
__launch_bounds__(256, 2)
__global__ void k_mid(const u16* __restrict__ xtb, const u16* __restrict__ w1b,
                      const float* __restrict__ wf, const float* __restrict__ w2ts,
                      const float* __restrict__ vd2p,
                      float* __restrict__ iproj, float* __restrict__ wps,
                      float* __restrict__ vd2) {
  __shared__ __align__(16) char smem[2*64*GK_*2];   // 64KB (gemm As+Bs)
  const int bid = blockIdx.x;
  const int t = threadIdx.x;
  if (bid < 208) {
    // ---- iproj = xtb(P,C) @ w1b^T(C,D), bf16 MFMA, BK=256, 64x64 tile ----
    u16* As = (u16*)smem;
    u16* Bs = As + 64*GK_;
    const int m0 = (bid >> 4) * 64, n0 = (bid & 15) * 64;
    const int wid = t >> 6, lane = t & 63;
    const int wm = wid >> 1, wn = wid & 1;
    const int lm = lane & 15, jr = lane >> 4;
    // staging: chunk c=i*256+t -> lds byte c*16; source chunk j = slot^(row&7)
    int offA[8], offB[8];
    u16* ldsA[8]; u16* ldsB[8];
    #pragma unroll
    for (int i = 0; i < 8; i++) {
      int c = i*256 + t;
      int row = c >> 5, js = c & 31;
      int j = js ^ (row & 7);
      offA[i] = (m0 + row) * C_ + j*8;
      offB[i] = (n0 + row) * C_ + j*8;
      ldsA[i] = &As[c*8];
      ldsB[i] = &Bs[c*8];
    }
    f32x4a acc[2][2] = {};
    for (int k0 = 0; k0 < C_; k0 += GK_) {
      #pragma unroll
      for (int i = 0; i < 8; i++)
        __builtin_amdgcn_global_load_lds((const __attribute__((address_space(1))) void*)(xtb + offA[i] + k0),
                                         (__attribute__((address_space(3))) void*)ldsA[i], 16, 0, 0);
      #pragma unroll
      for (int i = 0; i < 8; i++)
        __builtin_amdgcn_global_load_lds((const __attribute__((address_space(1))) void*)(w1b + offB[i] + k0),
                                         (__attribute__((address_space(3))) void*)ldsB[i], 16, 0, 0);
      __syncthreads();
      #pragma unroll
      for (int kk = 0; kk < 8; kk++) {
        int jx = ((kk*4 + jr) ^ (lm & 7)) * 8;
        s16x8 a0 = *(const s16x8*)&As[(wm*32 + lm)*GK_ + jx];
        s16x8 a1 = *(const s16x8*)&As[(wm*32 + 16 + lm)*GK_ + jx];
        s16x8 b0 = *(const s16x8*)&Bs[(wn*32 + lm)*GK_ + jx];
        s16x8 b1 = *(const s16x8*)&Bs[(wn*32 + 16 + lm)*GK_ + jx];
        acc[0][0] = __builtin_amdgcn_mfma_f32_16x16x32_bf16(a0, b0, acc[0][0], 0, 0, 0);
        acc[0][1] = __builtin_amdgcn_mfma_f32_16x16x32_bf16(a0, b1, acc[0][1], 0, 0, 0);
        acc[1][0] = __builtin_amdgcn_mfma_f32_16x16x32_bf16(a1, b0, acc[1][0], 0, 0, 0);
        acc[1][1] = __builtin_amdgcn_mfma_f32_16x16x32_bf16(a1, b1, acc[1][1], 0, 0, 0);
      }
      __syncthreads();
    }
    #pragma unroll
    for (int mi = 0; mi < 2; mi++)
      #pragma unroll
      for (int ni = 0; ni < 2; ni++)
        #pragma unroll
        for (int q = 0; q < 4; q++) {
          int prow = m0 + wm*32 + mi*16 + (lane>>4)*4 + q;
          int ncol = n0 + wn*32 + ni*16 + lm;
          if (prow < P_) iproj[(size_t)prow*D_ + ncol] = acc[mi][ni][q];
        }
  } else if (bid < 288) {
    // ---- wps[k,d] = sum_v wf[k,v]*w2ts[v,d] (scale folded into w2ts) ----
    float* wrow = (float*)smem;
    const int k = bid - 208;
    for (int i = t; i < WD_; i += 256) wrow[i] = wf[k*WD_ + i];
    __syncthreads();
    float4 acc = {0.f,0.f,0.f,0.f};
    const float4* w4 = (const float4*)w2ts;
    for (int v = 0; v < WD_; v++) {
      float s = wrow[v];
      float4 w = w4[(size_t)v*(D_/4) + t];
      acc.x = fmaf(s, w.x, acc.x); acc.y = fmaf(s, w.y, acc.y);
      acc.z = fmaf(s, w.z, acc.z); acc.w = fmaf(s, w.w, acc.w);
    }
    ((float4*)wps)[k*(D_/4) + t] = acc;
  } else {
    // ---- vd2[d] = -2 * sum_q vd2p[q][d] ----
    #pragma unroll
    for (int j = 0; j < 4; j++) {
      int d = j*256 + t;
      float s = 0.f;
      #pragma unroll
      for (int q = 0; q < 32; q++) s += vd2p[(size_t)q*D_ + d];
      vd2[d] = -2.0f * s;
    }
  }
}

// ======== coef[p,k] = sum_d vd2[d] * rcp(exp2(ip*wps)+1)   (S0 dropped:
// uniform shift cancels in softmax) ========================================
__launch_bounds__(320)
__global__ void k_coef(const float* __restrict__ iproj, const float* __restrict__ wps,
                       const float* __restrict__ vd2, float* __restrict__ coef) {
  __shared__ float ipd[D_];
  __shared__ float v2s[D_];
  const int p = blockIdx.x;
  const int t = threadIdx.x;
  for (int i = t; i < D_; i += 320) {
    ipd[i] = iproj[(size_t)p*D_ + i];
    v2s[i] = vd2[i];
  }
  __syncthreads();
  const int k = t >> 2, dq = t & 3;      // 4 lanes per k, each a 256-d quarter
  const float4* wv  = (const float4*)&wps[(size_t)k*D_ + dq*256];
  const float4* ip4 = (const float4*)&ipd[dq*256];
  const float4* v24 = (const float4*)&v2s[dq*256];
  float acc = 0.f;
  for (int q = 0; q < 64; q++) {
    float4 w  = wv[q];
    float4 ip = ip4[q];
    float4 v2 = v24[q];
    float r0 = __builtin_amdgcn_rcpf(__builtin_amdgcn_exp2f(ip.x*w.x) + 1.0f);
    float r1 = __builtin_amdgcn_rcpf(__builtin_amdgcn_exp2f(ip.y*w.y) + 1.0f);
    float r2 = __builtin_amdgcn_rcpf(__builtin_amdgcn_exp2f(ip.z*w.z) + 1.0f);
    float r3 = __builtin_amdgcn_rcpf(__builtin_amdgcn_exp2f(ip.w*w.w) + 1.0f);
    acc = fmaf(v2.x, r0, acc);
    acc = fmaf(v2.y, r1, acc);
    acc = fmaf(v2.z, r2, acc);
    acc = fmaf(v2.w, r3, acc);
  }
  acc += __shfl_xor(acc, 1);
  acc += __shfl_xor(acc, 2);
  if (dq == 0) coef[(size_t)p*K_ + k] = acc;
}

// ======== softmax over HW per (b,k) ========================================
__global__ void k_softmax(const float* __restrict__ coef, float* __restrict__ sm) {
  int bk = blockIdx.x; int b = bk / K_, k = bk % K_;
  int t = threadIdx.x;                  // 64 threads = 1 wave
  float v[4]; float mx = -1e30f;
  #pragma unroll
  for (int i = 0; i < 4; i++) {
    int hw = t + i*64;
    v[i] = (hw < HW_) ? coef[(size_t)(b*HW_ + hw)*K_ + k] : -1e30f;
    mx = fmaxf(mx, v[i]);
  }
  #pragma unroll
  for (int off = 32; off > 0; off >>= 1) mx = fmaxf(mx, __shfl_xor(mx, off));
  float e[4]; float sum = 0.f;
  #pragma unroll
  for (int i = 0; i < 4; i++) {
    int hw = t + i*64;
    e[i] = (hw < HW_) ? __builtin_amdgcn_exp2f((v[i]-mx)*1.4426950408889634f) : 0.f;
    sum += e[i];
  }
  #pragma unroll
  for (int off = 32; off > 0; off >>= 1) sum += __shfl_xor(sum, off);
  float rs = 1.0f / sum;
  #pragma unroll
  for (int i = 0; i < 4; i++) {
    int hw = t + i*64;
    if (hw < HW_) sm[(size_t)(b*HW_ + hw)*K_ + k] = e[i]*rs;
  }
}

// ======== fwc write + semantic (r9 structure) ==============================
// sem: 32 blocks, xt read once per (b,c-chunk), 80 k-accumulators.
// fwc: grid-stride global-address-order nt sweep, 1xfloat4 per thread per
// instruction (16B/lane wave-contiguous), unrolled x4 ACROSS grid-stride
// windows -> 4 independent lane-contiguous load->store chains in flight.
#define SEM_BLOCKS 32
#define FWC_BLOCKS 2048
__launch_bounds__(256)
__global__ void k_fwc_sem(const float* __restrict__ xt, const float* __restrict__ sm,
                          float* __restrict__ fwc, float* __restrict__ semantic) {
  const int bid = blockIdx.x;
  const int t = threadIdx.x;
  if (bid < SEM_BLOCKS) {
    // ---- semantic[b,k,c] = sum_hw xt[(b,hw),c]*sm[(b,hw),k] ----
    const int b = bid >> 3;
    const int c = (bid & 7) * 256 + t;
    float acc[K_];
    #pragma unroll
    for (int k = 0; k < K_; k++) acc[k] = 0.f;
    const float* smb = sm + (size_t)b*HW_*K_;
    const float* xb  = xt + (size_t)b*HW_*C_ + c;
    for (int hw = 0; hw < HW_; hw++) {
      float xv = xb[(size_t)hw*C_];
      #pragma unroll
      for (int k4 = 0; k4 < K_/4; k4++) {
        f32x4_t sv = *(const f32x4_t*)&smb[hw*K_ + k4*4];
        acc[k4*4+0] = fmaf(xv, sv.x, acc[k4*4+0]);
        acc[k4*4+1] = fmaf(xv, sv.y, acc[k4*4+1]);
        acc[k4*4+2] = fmaf(xv, sv.z, acc[k4*4+2]);
        acc[k4*4+3] = fmaf(xv, sv.w, acc[k4*4+3]);
      }
    }
    #pragma unroll
    for (int k = 0; k < K_; k++)
      semantic[((size_t)(b*K_ + k))*C_ + c] = acc[k];
  } else {
    // ---- fwc[p,k,c] = xt[p,c]*sm[p,k], nt sweep, 4 windows in flight ----
    const size_t N4 = (size_t)P_*K_*(C_/4);            // 32,112,640 float4
    const size_t S = (size_t)FWC_BLOCKS*256;           // 524288 (8MB window)
    size_t i4 = (size_t)(bid - SEM_BLOCKS)*256 + t;
    for (; i4 + 3*S < N4; i4 += 4*S) {
      #pragma unroll
      for (int u = 0; u < 4; u++) {
        size_t j4 = i4 + (size_t)u*S;
        int c4 = (int)(j4 & (C_/4 - 1));
        int pk = (int)(j4 >> 9);
        int p  = pk / K_;
        float s = sm[pk];
        f32x4_t xv = *(const f32x4_t*)&xt[(size_t)p*C_ + c4*4];
        __builtin_nontemporal_store(xv * s, (f32x4_t*)&fwc[j4*4]);
      }
    }
    for (; i4 < N4; i4 += S) {
      int c4 = (int)(i4 & (C_/4 - 1));
      int pk = (int)(i4 >> 9);
      int p  = pk / K_;
      float s = sm[pk];
      f32x4_t xv = *(const f32x4_t*)&xt[(size_t)p*C_ + c4*4];
      __builtin_nontemporal_store(xv * s, (f32x4_t*)&fwc[i4*4]);
    }
  }
}

extern "C" void kernel_launch(void* const* d_in, const int* in_sizes, int n_in,
                              void* d_out, int out_size, void* d_ws, size_t ws_size,
                              hipStream_t stream) {
  const float* img  = (const float*)d_in[0];
  const float* wf   = (const float*)d_in[1];
  const float* W1   = (const float*)d_in[2];
  const float* W2   = (const float*)d_in[3];
  const float* W3   = (const float*)d_in[4];
  const float* W4   = (const float*)d_in[6];

  float* out = (float*)d_out;
  float* semantic = out;                                    // B*K*C
  float* fwc      = out + (size_t)B_*K_*C_;                 // B*HW*K*C
  float* sm       = fwc + (size_t)P_*K_*C_;                 // B*HW*K

  float* ws    = (float*)d_ws;
  float* xt    = ws + XT_OFF;
  u16*   xtb   = (u16*)(ws + XTB_OFF);
  u16*   w1b   = (u16*)(ws + W1B_OFF);
  float* iproj = ws + IPROJ_OFF;
  float* w2ts  = ws + W2TS_OFF;
  float* wps   = ws + WPS_OFF;
  float* vd2   = ws + VD2_OFF;
  float* vd2p  = ws + VD2P_OFF;
  float* coef  = ws + COEF_OFF;

  k_prep<<<PREP_BLOCKS, 256, 0, stream>>>(img, W1, W2, W3, W4, xt, xtb, w1b, w2ts, vd2p);
  k_mid<<<MID_BLOCKS, 256, 0, stream>>>(xtb, w1b, wf, w2ts, vd2p, iproj, wps, vd2);
  k_coef<<<P_, 320, 0, stream>>>(iproj, wps, vd2, coef);
  k_softmax<<<B_*K_, 64, 0, stream>>>(coef, sm);
  k_fwc_sem<<<SEM_BLOCKS + FWC_BLOCKS, 256, 0, stream>>>(xt, sm, fwc, semantic);
}

// Round 15
// 174.987 us; speedup vs baseline: 2.4872x; 1.2173x over previous
//
#include <hip/hip_runtime.h>
#include <hip/hip_bf16.h>

// Problem constants
#define B_   4
#define C_   2048
#define HH_  14
#define HW_  196      // 14*14
#define P_   784      // B_*HW_
#define PPAD_ 832     // 13*64 (gemm M padding)
#define K_   80
#define WD_  300
#define D_   1024

typedef float f32x4_t __attribute__((ext_vector_type(4)));
typedef short s16x8  __attribute__((ext_vector_type(8)));
typedef float f32x4a __attribute__((ext_vector_type(4)));
typedef unsigned short u16;
typedef u16 u16x4 __attribute__((ext_vector_type(4)));
typedef u16 u16x8 __attribute__((ext_vector_type(8)));

// ws layout (in float units)
#define XT_OFF    0                          // P_*C_        = 1605632
#define XTB_OFF   (XT_OFF + P_*C_)           // PPAD_*C_ u16
#define W1B_OFF   (XTB_OFF + (PPAD_*C_)/2)   // D_*C_ u16
#define IPROJ_OFF (W1B_OFF + (D_*C_)/2)      // P_*D_
#define W2TS_OFF  (IPROJ_OFF + P_*D_)        // WD_*D_
#define WPS_OFF   (W2TS_OFF + WD_*D_)        // K_*D_
#define VD2_OFF   (WPS_OFF + K_*D_)          // D_
#define VD2P_OFF  (VD2_OFF + D_)             // 32*D_
#define COEF_OFF  (VD2P_OFF + 32*D_)         // P_*K_

static __device__ __forceinline__ u16 f2bf(float x) {
  __hip_bfloat16 h = __float2bfloat16(x);
  return *(u16*)&h;
}

// ======== merged prep: roles by blockIdx.x =================================
// [0,2048)        : W1 fp32 -> bf16
// [2048,3840)     : transpose img -> xt fp32 + xtb bf16
// [3840,4160)     : transpose+scale W2 -> w2ts
// [4160,4288)     : vd2 partials: part[e/32][d] = sum_{32 e} W4[e]*W3[e,d]
// [4288,4296)     : zero xtb pad rows 784..831
#define PREP_BLOCKS 4296
__launch_bounds__(256)
__global__ void k_prep(const float* __restrict__ img, const float* __restrict__ W1,
                       const float* __restrict__ W2, const float* __restrict__ W3,
                       const float* __restrict__ W4,
                       float* __restrict__ xt, u16* __restrict__ xtb,
                       u16* __restrict__ w1b, float* __restrict__ w2ts,
                       float* __restrict__ vd2p) {
  __shared__ float tile[32][33];
  const int bid = blockIdx.x;
  const int t = threadIdx.x;
  if (bid < 2048) {                       // ---- W1 -> bf16
    int i = bid*256 + t;
    f32x4_t v = *(const f32x4_t*)&W1[(size_t)i*4];
    u16x4 o = { f2bf(v.x), f2bf(v.y), f2bf(v.z), f2bf(v.w) };
    *(u16x4*)&w1b[(size_t)i*4] = o;
  } else if (bid < 3840) {                // ---- transpose x
    int r = bid - 2048;
    int c0 = (r & 63) * 32;
    int hw0 = ((r >> 6) % 7) * 32;
    int b = r / 448;
    int tx = t & 31, ty = t >> 5;
    #pragma unroll
    for (int i = 0; i < 4; i++) {
      int c = c0 + ty + i*8, hw = hw0 + tx;
      float v = 0.f;
      if (hw < HW_) v = img[((size_t)b*C_ + c)*HW_ + hw];
      tile[ty + i*8][tx] = v;
    }
    __syncthreads();
    #pragma unroll
    for (int i = 0; i < 4; i++) {
      int hw = hw0 + ty + i*8, c = c0 + tx;
      if (hw < HW_) {
        float v = tile[tx][ty + i*8];
        size_t idx = ((size_t)(b*HW_ + hw))*C_ + c;
        xt[idx] = v;
        xtb[idx] = f2bf(v);
      }
    }
  } else if (bid < 4160) {                // ---- transpose+scale W2
    int r = bid - 3840;
    int d0 = (r & 31) * 32;
    int v0 = (r >> 5) * 32;
    int tx = t & 31, ty = t >> 5;
    #pragma unroll
    for (int i = 0; i < 4; i++) {
      int d = d0 + ty + i*8, v = v0 + tx;
      float val = 0.f;
      if (v < WD_) val = W2[(size_t)d*WD_ + v];
      tile[ty + i*8][tx] = val;
    }
    __syncthreads();
    const float s = 2.8853900817779268f;  // 2*log2(e)
    #pragma unroll
    for (int i = 0; i < 4; i++) {
      int v = v0 + ty + i*8, d = d0 + tx;
      if (v < WD_) w2ts[(size_t)v*D_ + d] = tile[tx][ty + i*8] * s;
    }
  } else if (bid < 4288) {                // ---- vd2 partials
    int r = bid - 4160;
    int d = (r & 3) * 256 + t;
    int e0 = (r >> 2) * 32;
    float acc = 0.f;
    #pragma unroll
    for (int q = 0; q < 32; q++)
      acc = fmaf(W4[e0 + q], W3[(size_t)(e0 + q)*D_ + d], acc);
    vd2p[(size_t)(r >> 2)*D_ + d] = acc;
  } else {                                // ---- zero xtb pad
    int r = bid - 4288;                   // 0..7
    u16x8 z = {0,0,0,0,0,0,0,0};
    #pragma unroll
    for (int i = 0; i < 6; i++) {
      size_t o = (size_t)P_*C_ + ((size_t)(r*256 + t)*6 + i)*8;
      *(u16x8*)&xtb[o] = z;
    }
  }
}

// ======== mid: gemm(208) + wproj(80) + vd2 finalize(1), role-split ========
#define GK_ 256
#define MID_BLOCKS 289
__launch_bounds__(256, 2)
__global__ void k_mid(const u16* __restrict__ xtb, const u16* __restrict__ w1b,
                      const float* __restrict__ wf, const float* __restrict__ w2ts,
                      const float* __restrict__ vd2p,
                      float* __restrict__ iproj, float* __restrict__ wps,
                      float* __restrict__ vd2) {
  __shared__ __align__(16) char smem[2*64*GK_*2];   // 64KB (gemm As+Bs)
  const int bid = blockIdx.x;
  const int t = threadIdx.x;
  if (bid < 208) {
    // ---- iproj = xtb(P,C) @ w1b^T(C,D), bf16 MFMA, BK=256, 64x64 tile ----
    u16* As = (u16*)smem;
    u16* Bs = As + 64*GK_;
    const int m0 = (bid >> 4) * 64, n0 = (bid & 15) * 64;
    const int wid = t >> 6, lane = t & 63;
    const int wm = wid >> 1, wn = wid & 1;
    const int lm = lane & 15, jr = lane >> 4;
    // staging: chunk c=i*256+t -> lds byte c*16; source chunk j = slot^(row&7)
    int offA[8], offB[8];
    u16* ldsA[8]; u16* ldsB[8];
    #pragma unroll
    for (int i = 0; i < 8; i++) {
      int c = i*256 + t;
      int row = c >> 5, js = c & 31;
      int j = js ^ (row & 7);
      offA[i] = (m0 + row) * C_ + j*8;
      offB[i] = (n0 + row) * C_ + j*8;
      ldsA[i] = &As[c*8];
      ldsB[i] = &Bs[c*8];
    }
    f32x4a acc[2][2] = {};
    for (int k0 = 0; k0 < C_; k0 += GK_) {
      #pragma unroll
      for (int i = 0; i < 8; i++)
        __builtin_amdgcn_global_load_lds((const __attribute__((address_space(1))) void*)(xtb + offA[i] + k0),
                                         (__attribute__((address_space(3))) void*)ldsA[i], 16, 0, 0);
      #pragma unroll
      for (int i = 0; i < 8; i++)
        __builtin_amdgcn_global_load_lds((const __attribute__((address_space(1))) void*)(w1b + offB[i] + k0),
                                         (__attribute__((address_space(3))) void*)ldsB[i], 16, 0, 0);
      __syncthreads();
      #pragma unroll
      for (int kk = 0; kk < 8; kk++) {
        int jx = ((kk*4 + jr) ^ (lm & 7)) * 8;
        s16x8 a0 = *(const s16x8*)&As[(wm*32 + lm)*GK_ + jx];
        s16x8 a1 = *(const s16x8*)&As[(wm*32 + 16 + lm)*GK_ + jx];
        s16x8 b0 = *(const s16x8*)&Bs[(wn*32 + lm)*GK_ + jx];
        s16x8 b1 = *(const s16x8*)&Bs[(wn*32 + 16 + lm)*GK_ + jx];
        acc[0][0] = __builtin_amdgcn_mfma_f32_16x16x32_bf16(a0, b0, acc[0][0], 0, 0, 0);
        acc[0][1] = __builtin_amdgcn_mfma_f32_16x16x32_bf16(a0, b1, acc[0][1], 0, 0, 0);
        acc[1][0] = __builtin_amdgcn_mfma_f32_16x16x32_bf16(a1, b0, acc[1][0], 0, 0, 0);
        acc[1][1] = __builtin_amdgcn_mfma_f32_16x16x32_bf16(a1, b1, acc[1][1], 0, 0, 0);
      }
      __syncthreads();
    }
    #pragma unroll
    for (int mi = 0; mi < 2; mi++)
      #pragma unroll
      for (int ni = 0; ni < 2; ni++)
        #pragma unroll
        for (int q = 0; q < 4; q++) {
          int prow = m0 + wm*32 + mi*16 + (lane>>4)*4 + q;
          int ncol = n0 + wn*32 + ni*16 + lm;
          if (prow < P_) iproj[(size_t)prow*D_ + ncol] = acc[mi][ni][q];
        }
  } else if (bid < 288) {
    // ---- wps[k,d] = sum_v wf[k,v]*w2ts[v,d] (scale folded into w2ts) ----
    float* wrow = (float*)smem;
    const int k = bid - 208;
    for (int i = t; i < WD_; i += 256) wrow[i] = wf[k*WD_ + i];
    __syncthreads();
    float4 acc = {0.f,0.f,0.f,0.f};
    const float4* w4 = (const float4*)w2ts;
    for (int v = 0; v < WD_; v++) {
      float s = wrow[v];
      float4 w = w4[(size_t)v*(D_/4) + t];
      acc.x = fmaf(s, w.x, acc.x); acc.y = fmaf(s, w.y, acc.y);
      acc.z = fmaf(s, w.z, acc.z); acc.w = fmaf(s, w.w, acc.w);
    }
    ((float4*)wps)[k*(D_/4) + t] = acc;
  } else {
    // ---- vd2[d] = -2 * sum_q vd2p[q][d] ----
    #pragma unroll
    for (int j = 0; j < 4; j++) {
      int d = j*256 + t;
      float s = 0.f;
      #pragma unroll
      for (int q = 0; q < 32; q++) s += vd2p[(size_t)q*D_ + d];
      vd2[d] = -2.0f * s;
    }
  }
}

// ======== coef[p,k] = sum_d vd2[d] * rcp(exp2(ip*wps)+1)   (S0 dropped:
// uniform shift cancels in softmax) ========================================
__launch_bounds__(320)
__global__ void k_coef(const float* __restrict__ iproj, const float* __restrict__ wps,
                       const float* __restrict__ vd2, float* __restrict__ coef) {
  __shared__ float ipd[D_];
  __shared__ float v2s[D_];
  const int p = blockIdx.x;
  const int t = threadIdx.x;
  for (int i = t; i < D_; i += 320) {
    ipd[i] = iproj[(size_t)p*D_ + i];
    v2s[i] = vd2[i];
  }
  __syncthreads();
  const int k = t >> 2, dq = t & 3;      // 4 lanes per k, each a 256-d quarter
  const float4* wv  = (const float4*)&wps[(size_t)k*D_ + dq*256];
  const float4* ip4 = (const float4*)&ipd[dq*256];
  const float4* v24 = (const float4*)&v2s[dq*256];
  float acc = 0.f;
  for (int q = 0; q < 64; q++) {
    float4 w  = wv[q];
    float4 ip = ip4[q];
    float4 v2 = v24[q];
    float r0 = __builtin_amdgcn_rcpf(__builtin_amdgcn_exp2f(ip.x*w.x) + 1.0f);
    float r1 = __builtin_amdgcn_rcpf(__builtin_amdgcn_exp2f(ip.y*w.y) + 1.0f);
    float r2 = __builtin_amdgcn_rcpf(__builtin_amdgcn_exp2f(ip.z*w.z) + 1.0f);
    float r3 = __builtin_amdgcn_rcpf(__builtin_amdgcn_exp2f(ip.w*w.w) + 1.0f);
    acc = fmaf(v2.x, r0, acc);
    acc = fmaf(v2.y, r1, acc);
    acc = fmaf(v2.z, r2, acc);
    acc = fmaf(v2.w, r3, acc);
  }
  acc += __shfl_xor(acc, 1);
  acc += __shfl_xor(acc, 2);
  if (dq == 0) coef[(size_t)p*K_ + k] = acc;
}

// ======== softmax over HW per (b,k) ========================================
__global__ void k_softmax(const float* __restrict__ coef, float* __restrict__ sm) {
  int bk = blockIdx.x; int b = bk / K_, k = bk % K_;
  int t = threadIdx.x;                  // 64 threads = 1 wave
  float v[4]; float mx = -1e30f;
  #pragma unroll
  for (int i = 0; i < 4; i++) {
    int hw = t + i*64;
    v[i] = (hw < HW_) ? coef[(size_t)(b*HW_ + hw)*K_ + k] : -1e30f;
    mx = fmaxf(mx, v[i]);
  }
  #pragma unroll
  for (int off = 32; off > 0; off >>= 1) mx = fmaxf(mx, __shfl_xor(mx, off));
  float e[4]; float sum = 0.f;
  #pragma unroll
  for (int i = 0; i < 4; i++) {
    int hw = t + i*64;
    e[i] = (hw < HW_) ? __builtin_amdgcn_exp2f((v[i]-mx)*1.4426950408889634f) : 0.f;
    sum += e[i];
  }
  #pragma unroll
  for (int off = 32; off > 0; off >>= 1) sum += __shfl_xor(sum, off);
  float rs = 1.0f / sum;
  #pragma unroll
  for (int i = 0; i < 4; i++) {
    int hw = t + i*64;
    if (hw < HW_) sm[(size_t)(b*HW_ + hw)*K_ + k] = e[i]*rs;
  }
}

// ======== fwc write + semantic (r9 structure; window-size probe) ===========
// sem: 32 blocks, xt read once per (b,c-chunk), 80 k-accumulators.
// fwc: grid-stride global-address-order nt sweep, 1xfloat4/thread.
// PROBE: FWC_BLOCKS 2048 -> 1024 (instantaneous write window 8MB -> 4MB).
#define SEM_BLOCKS 32
#define FWC_BLOCKS 1024
__launch_bounds__(256)
__global__ void k_fwc_sem(const float* __restrict__ xt, const float* __restrict__ sm,
                          float* __restrict__ fwc, float* __restrict__ semantic) {
  const int bid = blockIdx.x;
  const int t = threadIdx.x;
  if (bid < SEM_BLOCKS) {
    // ---- semantic[b,k,c] = sum_hw xt[(b,hw),c]*sm[(b,hw),k] ----
    const int b = bid >> 3;
    const int c = (bid & 7) * 256 + t;
    float acc[K_];
    #pragma unroll
    for (int k = 0; k < K_; k++) acc[k] = 0.f;
    const float* smb = sm + (size_t)b*HW_*K_;
    const float* xb  = xt + (size_t)b*HW_*C_ + c;
    for (int hw = 0; hw < HW_; hw++) {
      float xv = xb[(size_t)hw*C_];
      #pragma unroll
      for (int k4 = 0; k4 < K_/4; k4++) {
        f32x4_t sv = *(const f32x4_t*)&smb[hw*K_ + k4*4];
        acc[k4*4+0] = fmaf(xv, sv.x, acc[k4*4+0]);
        acc[k4*4+1] = fmaf(xv, sv.y, acc[k4*4+1]);
        acc[k4*4+2] = fmaf(xv, sv.z, acc[k4*4+2]);
        acc[k4*4+3] = fmaf(xv, sv.w, acc[k4*4+3]);
      }
    }
    #pragma unroll
    for (int k = 0; k < K_; k++)
      semantic[((size_t)(b*K_ + k))*C_ + c] = acc[k];
  } else {
    // ---- fwc[p,k,c] = xt[p,c]*sm[p,k], linear nt sweep ----
    const size_t N4 = (size_t)P_*K_*(C_/4);            // 32,112,640 float4
    const size_t stride4 = (size_t)FWC_BLOCKS*256;
    size_t i4 = (size_t)(bid - SEM_BLOCKS)*256 + t;
    for (; i4 < N4; i4 += stride4) {
      int c4 = (int)(i4 & (C_/4 - 1));                 // 0..511
      int pk = (int)(i4 >> 9);                         // p*K_ + k
      int p  = pk / K_;                                // magic-mul div
      float s = sm[pk];                                // sm is pk-linear
      f32x4_t xv = *(const f32x4_t*)&xt[(size_t)p*C_ + c4*4];
      __builtin_nontemporal_store(xv * s, (f32x4_t*)&fwc[i4*4]);
    }
  }
}

extern "C" void kernel_launch(void* const* d_in, const int* in_sizes, int n_in,
                              void* d_out, int out_size, void* d_ws, size_t ws_size,
                              hipStream_t stream) {
  const float* img  = (const float*)d_in[0];
  const float* wf   = (const float*)d_in[1];
  const float* W1   = (const float*)d_in[2];
  const float* W2   = (const float*)d_in[3];
  const float* W3   = (const float*)d_in[4];
  const float* W4   = (const float*)d_in[6];

  float* out = (float*)d_out;
  float* semantic = out;                                    // B*K*C
  float* fwc      = out + (size_t)B_*K_*C_;                 // B*HW*K*C
  float* sm       = fwc + (size_t)P_*K_*C_;                 // B*HW*K

  float* ws    = (float*)d_ws;
  float* xt    = ws + XT_OFF;
  u16*   xtb   = (u16*)(ws + XTB_OFF);
  u16*   w1b   = (u16*)(ws + W1B_OFF);
  float* iproj = ws + IPROJ_OFF;
  float* w2ts  = ws + W2TS_OFF;
  float* wps   = ws + WPS_OFF;
  float* vd2   = ws + VD2_OFF;
  float* vd2p  = ws + VD2P_OFF;
  float* coef  = ws + COEF_OFF;

  k_prep<<<PREP_BLOCKS, 256, 0, stream>>>(img, W1, W2, W3, W4, xt, xtb, w1b, w2ts, vd2p);
  k_mid<<<MID_BLOCKS, 256, 0, stream>>>(xtb, w1b, wf, w2ts, vd2p, iproj, wps, vd2);
  k_coef<<<P_, 320, 0, stream>>>(iproj, wps, vd2, coef);
  k_softmax<<<B_*K_, 64, 0, stream>>>(coef, sm);
  k_fwc_sem<<<SEM_BLOCKS + FWC_BLOCKS, 256, 0, stream>>>(xt, sm, fwc, semantic);
}

// Round 16
// 163.460 us; speedup vs baseline: 2.6626x; 1.0705x over previous
//
#include <hip/hip_runtime.h>
#include <hip/hip_bf16.h>

// Problem constants
#define B_   4
#define C_   2048
#define HH_  14
#define HW_  196      // 14*14
#define P_   784      // B_*HW_
#define PPAD_ 832     // 13*64 (gemm M padding)
#define K_   80
#define WD_  300
#define D_   1024

typedef float f32x4_t __attribute__((ext_vector_type(4)));
typedef short s16x8  __attribute__((ext_vector_type(8)));
typedef float f32x4a __attribute__((ext_vector_type(4)));
typedef unsigned short u16;
typedef u16 u16x4 __attribute__((ext_vector_type(4)));
typedef u16 u16x8 __attribute__((ext_vector_type(8)));

// ws layout (in float units)
#define XT_OFF    0                          // P_*C_        = 1605632
#define XTB_OFF   (XT_OFF + P_*C_)           // PPAD_*C_ u16
#define W1B_OFF   (XTB_OFF + (PPAD_*C_)/2)   // D_*C_ u16
#define IPROJ_OFF (W1B_OFF + (D_*C_)/2)      // P_*D_
#define W2TS_OFF  (IPROJ_OFF + P_*D_)        // WD_*D_
#define WPS_OFF   (W2TS_OFF + WD_*D_)        // K_*D_
#define VD2_OFF   (WPS_OFF + K_*D_)          // D_
#define VD2P_OFF  (VD2_OFF + D_)             // 32*D_
#define COEF_OFF  (VD2P_OFF + 32*D_)         // P_*K_

static __device__ __forceinline__ u16 f2bf(float x) {
  __hip_bfloat16 h = __float2bfloat16(x);
  return *(u16*)&h;
}

// ======== merged prep: roles by blockIdx.x =================================
// [0,2048)        : W1 fp32 -> bf16
// [2048,3840)     : transpose img -> xt fp32 + xtb bf16
// [3840,4160)     : transpose+scale W2 -> w2ts
// [4160,4288)     : vd2 partials: part[e/32][d] = sum_{32 e} W4[e]*W3[e,d]
// [4288,4296)     : zero xtb pad rows 784..831
#define PREP_BLOCKS 4296
__launch_bounds__(256)
__global__ void k_prep(const float* __restrict__ img, const float* __restrict__ W1,
                       const float* __restrict__ W2, const float* __restrict__ W3,
                       const float* __restrict__ W4,
                       float* __restrict__ xt, u16* __restrict__ xtb,
                       u16* __restrict__ w1b, float* __restrict__ w2ts,
                       float* __restrict__ vd2p) {
  __shared__ float tile[32][33];
  const int bid = blockIdx.x;
  const int t = threadIdx.x;
  if (bid < 2048) {                       // ---- W1 -> bf16
    int i = bid*256 + t;
    f32x4_t v = *(const f32x4_t*)&W1[(size_t)i*4];
    u16x4 o = { f2bf(v.x), f2bf(v.y), f2bf(v.z), f2bf(v.w) };
    *(u16x4*)&w1b[(size_t)i*4] = o;
  } else if (bid < 3840) {                // ---- transpose x
    int r = bid - 2048;
    int c0 = (r & 63) * 32;
    int hw0 = ((r >> 6) % 7) * 32;
    int b = r / 448;
    int tx = t & 31, ty = t >> 5;
    #pragma unroll
    for (int i = 0; i < 4; i++) {
      int c = c0 + ty + i*8, hw = hw0 + tx;
      float v = 0.f;
      if (hw < HW_) v = img[((size_t)b*C_ + c)*HW_ + hw];
      tile[ty + i*8][tx] = v;
    }
    __syncthreads();
    #pragma unroll
    for (int i = 0; i < 4; i++) {
      int hw = hw0 + ty + i*8, c = c0 + tx;
      if (hw < HW_) {
        float v = tile[tx][ty + i*8];
        size_t idx = ((size_t)(b*HW_ + hw))*C_ + c;
        xt[idx] = v;
        xtb[idx] = f2bf(v);
      }
    }
  } else if (bid < 4160) {                // ---- transpose+scale W2
    int r = bid - 3840;
    int d0 = (r & 31) * 32;
    int v0 = (r >> 5) * 32;
    int tx = t & 31, ty = t >> 5;
    #pragma unroll
    for (int i = 0; i < 4; i++) {
      int d = d0 + ty + i*8, v = v0 + tx;
      float val = 0.f;
      if (v < WD_) val = W2[(size_t)d*WD_ + v];
      tile[ty + i*8][tx] = val;
    }
    __syncthreads();
    const float s = 2.8853900817779268f;  // 2*log2(e)
    #pragma unroll
    for (int i = 0; i < 4; i++) {
      int v = v0 + ty + i*8, d = d0 + tx;
      if (v < WD_) w2ts[(size_t)v*D_ + d] = tile[tx][ty + i*8] * s;
    }
  } else if (bid < 4288) {                // ---- vd2 partials
    int r = bid - 4160;
    int d = (r & 3) * 256 + t;
    int e0 = (r >> 2) * 32;
    float acc = 0.f;
    #pragma unroll
    for (int q = 0; q < 32; q++)
      acc = fmaf(W4[e0 + q], W3[(size_t)(e0 + q)*D_ + d], acc);
    vd2p[(size_t)(r >> 2)*D_ + d] = acc;
  } else {                                // ---- zero xtb pad
    int r = bid - 4288;                   // 0..7
    u16x8 z = {0,0,0,0,0,0,0,0};
    #pragma unroll
    for (int i = 0; i < 6; i++) {
      size_t o = (size_t)P_*C_ + ((size_t)(r*256 + t)*6 + i)*8;
      *(u16x8*)&xtb[o] = z;
    }
  }
}

// ======== mid: gemm(208) + wproj(80) + vd2 finalize(1), role-split ========
#define GK_ 256
#define MID_BLOCKS 289
__launch_bounds__(256, 2)
__global__ void k_mid(const u16* __restrict__ xtb, const u16* __restrict__ w1b,
                      const float* __restrict__ wf, const float* __restrict__ w2ts,
                      const float* __restrict__ vd2p,
                      float* __restrict__ iproj, float* __restrict__ wps,
                      float* __restrict__ vd2) {
  __shared__ __align__(16) char smem[2*64*GK_*2];   // 64KB (gemm As+Bs)
  const int bid = blockIdx.x;
  const int t = threadIdx.x;
  if (bid < 208) {
    // ---- iproj = xtb(P,C) @ w1b^T(C,D), bf16 MFMA, BK=256, 64x64 tile ----
    u16* As = (u16*)smem;
    u16* Bs = As + 64*GK_;
    const int m0 = (bid >> 4) * 64, n0 = (bid & 15) * 64;
    const int wid = t >> 6, lane = t & 63;
    const int wm = wid >> 1, wn = wid & 1;
    const int lm = lane & 15, jr = lane >> 4;
    // staging: chunk c=i*256+t -> lds byte c*16; source chunk j = slot^(row&7)
    int offA[8], offB[8];
    u16* ldsA[8]; u16* ldsB[8];
    #pragma unroll
    for (int i = 0; i < 8; i++) {
      int c = i*256 + t;
      int row = c >> 5, js = c & 31;
      int j = js ^ (row & 7);
      offA[i] = (m0 + row) * C_ + j*8;
      offB[i] = (n0 + row) * C_ + j*8;
      ldsA[i] = &As[c*8];
      ldsB[i] = &Bs[c*8];
    }
    f32x4a acc[2][2] = {};
    for (int k0 = 0; k0 < C_; k0 += GK_) {
      #pragma unroll
      for (int i = 0; i < 8; i++)
        __builtin_amdgcn_global_load_lds((const __attribute__((address_space(1))) void*)(xtb + offA[i] + k0),
                                         (__attribute__((address_space(3))) void*)ldsA[i], 16, 0, 0);
      #pragma unroll
      for (int i = 0; i < 8; i++)
        __builtin_amdgcn_global_load_lds((const __attribute__((address_space(1))) void*)(w1b + offB[i] + k0),
                                         (__attribute__((address_space(3))) void*)ldsB[i], 16, 0, 0);
      __syncthreads();
      #pragma unroll
      for (int kk = 0; kk < 8; kk++) {
        int jx = ((kk*4 + jr) ^ (lm & 7)) * 8;
        s16x8 a0 = *(const s16x8*)&As[(wm*32 + lm)*GK_ + jx];
        s16x8 a1 = *(const s16x8*)&As[(wm*32 + 16 + lm)*GK_ + jx];
        s16x8 b0 = *(const s16x8*)&Bs[(wn*32 + lm)*GK_ + jx];
        s16x8 b1 = *(const s16x8*)&Bs[(wn*32 + 16 + lm)*GK_ + jx];
        acc[0][0] = __builtin_amdgcn_mfma_f32_16x16x32_bf16(a0, b0, acc[0][0], 0, 0, 0);
        acc[0][1] = __builtin_amdgcn_mfma_f32_16x16x32_bf16(a0, b1, acc[0][1], 0, 0, 0);
        acc[1][0] = __builtin_amdgcn_mfma_f32_16x16x32_bf16(a1, b0, acc[1][0], 0, 0, 0);
        acc[1][1] = __builtin_amdgcn_mfma_f32_16x16x32_bf16(a1, b1, acc[1][1], 0, 0, 0);
      }
      __syncthreads();
    }
    #pragma unroll
    for (int mi = 0; mi < 2; mi++)
      #pragma unroll
      for (int ni = 0; ni < 2; ni++)
        #pragma unroll
        for (int q = 0; q < 4; q++) {
          int prow = m0 + wm*32 + mi*16 + (lane>>4)*4 + q;
          int ncol = n0 + wn*32 + ni*16 + lm;
          if (prow < P_) iproj[(size_t)prow*D_ + ncol] = acc[mi][ni][q];
        }
  } else if (bid < 288) {
    // ---- wps[k,d] = sum_v wf[k,v]*w2ts[v,d] (scale folded into w2ts) ----
    float* wrow = (float*)smem;
    const int k = bid - 208;
    for (int i = t; i < WD_; i += 256) wrow[i] = wf[k*WD_ + i];
    __syncthreads();
    float4 acc = {0.f,0.f,0.f,0.f};
    const float4* w4 = (const float4*)w2ts;
    for (int v = 0; v < WD_; v++) {
      float s = wrow[v];
      float4 w = w4[(size_t)v*(D_/4) + t];
      acc.x = fmaf(s, w.x, acc.x); acc.y = fmaf(s, w.y, acc.y);
      acc.z = fmaf(s, w.z, acc.z); acc.w = fmaf(s, w.w, acc.w);
    }
    ((float4*)wps)[k*(D_/4) + t] = acc;
  } else {
    // ---- vd2[d] = -2 * sum_q vd2p[q][d] ----
    #pragma unroll
    for (int j = 0; j < 4; j++) {
      int d = j*256 + t;
      float s = 0.f;
      #pragma unroll
      for (int q = 0; q < 32; q++) s += vd2p[(size_t)q*D_ + d];
      vd2[d] = -2.0f * s;
    }
  }
}

// ======== coef[p,k] = sum_d vd2[d] * rcp(exp2(ip*wps)+1)   (S0 dropped:
// uniform shift cancels in softmax) ========================================
__launch_bounds__(320)
__global__ void k_coef(const float* __restrict__ iproj, const float* __restrict__ wps,
                       const float* __restrict__ vd2, float* __restrict__ coef) {
  __shared__ float ipd[D_];
  __shared__ float v2s[D_];
  const int p = blockIdx.x;
  const int t = threadIdx.x;
  for (int i = t; i < D_; i += 320) {
    ipd[i] = iproj[(size_t)p*D_ + i];
    v2s[i] = vd2[i];
  }
  __syncthreads();
  const int k = t >> 2, dq = t & 3;      // 4 lanes per k, each a 256-d quarter
  const float4* wv  = (const float4*)&wps[(size_t)k*D_ + dq*256];
  const float4* ip4 = (const float4*)&ipd[dq*256];
  const float4* v24 = (const float4*)&v2s[dq*256];
  float acc = 0.f;
  for (int q = 0; q < 64; q++) {
    float4 w  = wv[q];
    float4 ip = ip4[q];
    float4 v2 = v24[q];
    float r0 = __builtin_amdgcn_rcpf(__builtin_amdgcn_exp2f(ip.x*w.x) + 1.0f);
    float r1 = __builtin_amdgcn_rcpf(__builtin_amdgcn_exp2f(ip.y*w.y) + 1.0f);
    float r2 = __builtin_amdgcn_rcpf(__builtin_amdgcn_exp2f(ip.z*w.z) + 1.0f);
    float r3 = __builtin_amdgcn_rcpf(__builtin_amdgcn_exp2f(ip.w*w.w) + 1.0f);
    acc = fmaf(v2.x, r0, acc);
    acc = fmaf(v2.y, r1, acc);
    acc = fmaf(v2.z, r2, acc);
    acc = fmaf(v2.w, r3, acc);
  }
  acc += __shfl_xor(acc, 1);
  acc += __shfl_xor(acc, 2);
  if (dq == 0) coef[(size_t)p*K_ + k] = acc;
}

// ======== softmax over HW per (b,k) ========================================
__global__ void k_softmax(const float* __restrict__ coef, float* __restrict__ sm) {
  int bk = blockIdx.x; int b = bk / K_, k = bk % K_;
  int t = threadIdx.x;                  // 64 threads = 1 wave
  float v[4]; float mx = -1e30f;
  #pragma unroll
  for (int i = 0; i < 4; i++) {
    int hw = t + i*64;
    v[i] = (hw < HW_) ? coef[(size_t)(b*HW_ + hw)*K_ + k] : -1e30f;
    mx = fmaxf(mx, v[i]);
  }
  #pragma unroll
  for (int off = 32; off > 0; off >>= 1) mx = fmaxf(mx, __shfl_xor(mx, off));
  float e[4]; float sum = 0.f;
  #pragma unroll
  for (int i = 0; i < 4; i++) {
    int hw = t + i*64;
    e[i] = (hw < HW_) ? __builtin_amdgcn_exp2f((v[i]-mx)*1.4426950408889634f) : 0.f;
    sum += e[i];
  }
  #pragma unroll
  for (int off = 32; off > 0; off >>= 1) sum += __shfl_xor(sum, off);
  float rs = 1.0f / sum;
  #pragma unroll
  for (int i = 0; i < 4; i++) {
    int hw = t + i*64;
    if (hw < HW_) sm[(size_t)(b*HW_ + hw)*K_ + k] = e[i]*rs;
  }
}

// ======== fwc write + semantic (r9 structure; window-size probe) ===========
// sem: 32 blocks, xt read once per (b,c-chunk), 80 k-accumulators.
// fwc: grid-stride global-address-order nt sweep, 1xfloat4/thread.
// Window-size curve so far: 32MB=213us, 8MB=183, 4MB=175. PROBE: 2MB (512).
#define SEM_BLOCKS 32
#define FWC_BLOCKS 512
__launch_bounds__(256)
__global__ void k_fwc_sem(const float* __restrict__ xt, const float* __restrict__ sm,
                          float* __restrict__ fwc, float* __restrict__ semantic) {
  const int bid = blockIdx.x;
  const int t = threadIdx.x;
  if (bid < SEM_BLOCKS) {
    // ---- semantic[b,k,c] = sum_hw xt[(b,hw),c]*sm[(b,hw),k] ----
    const int b = bid >> 3;
    const int c = (bid & 7) * 256 + t;
    float acc[K_];
    #pragma unroll
    for (int k = 0; k < K_; k++) acc[k] = 0.f;
    const float* smb = sm + (size_t)b*HW_*K_;
    const float* xb  = xt + (size_t)b*HW_*C_ + c;
    for (int hw = 0; hw < HW_; hw++) {
      float xv = xb[(size_t)hw*C_];
      #pragma unroll
      for (int k4 = 0; k4 < K_/4; k4++) {
        f32x4_t sv = *(const f32x4_t*)&smb[hw*K_ + k4*4];
        acc[k4*4+0] = fmaf(xv, sv.x, acc[k4*4+0]);
        acc[k4*4+1] = fmaf(xv, sv.y, acc[k4*4+1]);
        acc[k4*4+2] = fmaf(xv, sv.z, acc[k4*4+2]);
        acc[k4*4+3] = fmaf(xv, sv.w, acc[k4*4+3]);
      }
    }
    #pragma unroll
    for (int k = 0; k < K_; k++)
      semantic[((size_t)(b*K_ + k))*C_ + c] = acc[k];
  } else {
    // ---- fwc[p,k,c] = xt[p,c]*sm[p,k], linear nt sweep ----
    const size_t N4 = (size_t)P_*K_*(C_/4);            // 32,112,640 float4
    const size_t stride4 = (size_t)FWC_BLOCKS*256;
    size_t i4 = (size_t)(bid - SEM_BLOCKS)*256 + t;
    for (; i4 < N4; i4 += stride4) {
      int c4 = (int)(i4 & (C_/4 - 1));                 // 0..511
      int pk = (int)(i4 >> 9);                         // p*K_ + k
      int p  = pk / K_;                                // magic-mul div
      float s = sm[pk];                                // sm is pk-linear
      f32x4_t xv = *(const f32x4_t*)&xt[(size_t)p*C_ + c4*4];
      __builtin_nontemporal_store(xv * s, (f32x4_t*)&fwc[i4*4]);
    }
  }
}

extern "C" void kernel_launch(void* const* d_in, const int* in_sizes, int n_in,
                              void* d_out, int out_size, void* d_ws, size_t ws_size,
                              hipStream_t stream) {
  const float* img  = (const float*)d_in[0];
  const float* wf   = (const float*)d_in[1];
  const float* W1   = (const float*)d_in[2];
  const float* W2   = (const float*)d_in[3];
  const float* W3   = (const float*)d_in[4];
  const float* W4   = (const float*)d_in[6];

  float* out = (float*)d_out;
  float* semantic = out;                                    // B*K*C
  float* fwc      = out + (size_t)B_*K_*C_;                 // B*HW*K*C
  float* sm       = fwc + (size_t)P_*K_*C_;                 // B*HW*K

  float* ws    = (float*)d_ws;
  float* xt    = ws + XT_OFF;
  u16*   xtb   = (u16*)(ws + XTB_OFF);
  u16*   w1b   = (u16*)(ws + W1B_OFF);
  float* iproj = ws + IPROJ_OFF;
  float* w2ts  = ws + W2TS_OFF;
  float* wps   = ws + WPS_OFF;
  float* vd2   = ws + VD2_OFF;
  float* vd2p  = ws + VD2P_OFF;
  float* coef  = ws + COEF_OFF;

  k_prep<<<PREP_BLOCKS, 256, 0, stream>>>(img, W1, W2, W3, W4, xt, xtb, w1b, w2ts, vd2p);
  k_mid<<<MID_BLOCKS, 256, 0, stream>>>(xtb, w1b, wf, w2ts, vd2p, iproj, wps, vd2);
  k_coef<<<P_, 320, 0, stream>>>(iproj, wps, vd2, coef);
  k_softmax<<<B_*K_, 64, 0, stream>>>(coef, sm);
  k_fwc_sem<<<SEM_BLOCKS + FWC_BLOCKS, 256, 0, stream>>>(xt, sm, fwc, semantic);
}